// Round 4
// baseline (160.189 us; speedup 1.0000x reference)
//
#include <hip/hip_runtime.h>
#include <math.h>

#define L_DIM   8192
#define NCH     64
#define M_TOT_F 262144.0f
#define EPS_F   1e-5f

typedef float f32x4 __attribute__((ext_vector_type(4)));
typedef short bf16x8 __attribute__((ext_vector_type(8)));

union U8 { unsigned u[4]; bf16x8 v; };

// split two fp32 into packed bf16 hi (truncated) and bf16 lo (residual), 2 shorts per u32
__device__ __forceinline__ void cvt2(float f0, float f1, unsigned& h, unsigned& l) {
    unsigned u0 = __float_as_uint(f0), u1 = __float_as_uint(f1);
    h = (u0 >> 16) | (u1 & 0xFFFF0000u);
    float r0 = f0 - __uint_as_float(u0 & 0xFFFF0000u);
    float r1 = f1 - __uint_as_float(u1 & 0xFFFF0000u);
    l = (__float_as_uint(r0) >> 16) | (__float_as_uint(r1) & 0xFFFF0000u);
}

__device__ __forceinline__ f32x4 mfma16(bf16x8 a, bf16x8 b, f32x4 c) {
    return __builtin_amdgcn_mfma_f32_16x16x32_bf16(a, b, c, 0, 0, 0);
}

__device__ __forceinline__ f32x4 fzero() {
    f32x4 z; z[0] = 0.f; z[1] = 0.f; z[2] = 0.f; z[3] = 0.f; return z;
}

// ---------------- K1: Gram partials (G1=hi*hi^T, G2=hi*lo^T) + row sums ----------------
#define GTPB 8
__global__ __launch_bounds__(256) void gram_kernel(const float* __restrict__ X,
                                                   float* __restrict__ P) {
    __shared__ __align__(16) unsigned short hplane[64 * 72];
    __shared__ __align__(16) unsigned short lplane[64 * 72];
    const int tid  = threadIdx.x;
    const int w    = tid >> 6;
    const int lane = tid & 63;
    const int m    = lane & 15;
    const int q    = lane >> 4;
    const int lrow = tid >> 2;
    const int lq16 = (tid & 3) << 4;

    f32x4 acc1[4], acc2[4];
#pragma unroll
    for (int nb = 0; nb < 4; ++nb) { acc1[nb] = fzero(); acc2[nb] = fzero(); }
    float sacc = 0.f;

    const int tile0 = blockIdx.x * GTPB;
    float4 v[4];
    {
        int t = tile0;
        const float* src = X + ((size_t)((t >> 7) * NCH + lrow)) * L_DIM + ((t & 127) << 6) + lq16;
#pragma unroll
        for (int i = 0; i < 4; ++i) v[i] = ((const float4*)src)[i];
    }

    for (int t = 0; t < GTPB; ++t) {
#pragma unroll
        for (int i = 0; i < 4; ++i) sacc += v[i].x + v[i].y + v[i].z + v[i].w;
        __syncthreads();
#pragma unroll
        for (int i = 0; i < 4; ++i) {
            unsigned h0, l0, h1, l1;
            cvt2(v[i].x, v[i].y, h0, l0);
            cvt2(v[i].z, v[i].w, h1, l1);
            uint2 hh; hh.x = h0; hh.y = h1;
            uint2 ll; ll.x = l0; ll.y = l1;
            *(uint2*)&hplane[lrow * 72 + lq16 + 4 * i] = hh;
            *(uint2*)&lplane[lrow * 72 + lq16 + 4 * i] = ll;
        }
        __syncthreads();
        if (t + 1 < GTPB) {
            int tn = tile0 + t + 1;
            const float* src = X + ((size_t)((tn >> 7) * NCH + lrow)) * L_DIM + ((tn & 127) << 6) + lq16;
#pragma unroll
            for (int i = 0; i < 4; ++i) v[i] = ((const float4*)src)[i];
        }
#pragma unroll
        for (int k0 = 0; k0 < 64; k0 += 32) {
            bf16x8 a = *(const bf16x8*)&hplane[(16 * w + m) * 72 + k0 + 8 * q];
#pragma unroll
            for (int nb = 0; nb < 4; ++nb) {
                bf16x8 bh = *(const bf16x8*)&hplane[(16 * nb + m) * 72 + k0 + 8 * q];
                bf16x8 bl = *(const bf16x8*)&lplane[(16 * nb + m) * 72 + k0 + 8 * q];
                acc1[nb] = mfma16(a, bh, acc1[nb]);
                acc2[nb] = mfma16(a, bl, acc2[nb]);
            }
        }
    }

    float* base = P + (size_t)blockIdx.x * 8256;
#pragma unroll
    for (int nb = 0; nb < 4; ++nb)
#pragma unroll
        for (int r = 0; r < 4; ++r) {
            int grow = 16 * w + 4 * q + r;
            int gcol = 16 * nb + m;
            base[grow * 64 + gcol]        = acc1[nb][r];
            base[4096 + grow * 64 + gcol] = acc2[nb][r];
        }
    sacc += __shfl_xor(sacc, 1);
    sacc += __shfl_xor(sacc, 2);
    if ((tid & 3) == 0) base[8192 + lrow] = sacc;
}

// ---------------- K1b: reduce 512 partials -> ws[0..8256) ----------------
__global__ __launch_bounds__(256) void reduce_kernel(const float* __restrict__ P,
                                                     float* __restrict__ ws) {
    const int tid = threadIdx.x;
    const int w = tid >> 6, lane = tid & 63;
    const int e0 = blockIdx.x * 64;
    float a = 0.f;
#pragma unroll 8
    for (int i = 0; i < 128; ++i)
        a += P[(size_t)(w * 128 + i) * 8256 + e0 + lane];
    __shared__ float red[4][64];
    red[w][lane] = a;
    __syncthreads();
    if (w == 0)
        ws[e0 + lane] = red[0][lane] + red[1][lane] + red[2][lane] + red[3][lane];
}

// ---------------- K2: Newton-Schulz, 1024 threads, bf16 hi/lo plane caches -------------
// 16 waves: wave = (s,g); s = row strip (16 rows), g = col block (16 cols).
// All iterates are symmetric -> both operands read row-wise from planes (stride 72).
__device__ __forceinline__ void ns_mm(unsigned short* __restrict__ Dh, unsigned short* __restrict__ Dl,
                                      const unsigned short* __restrict__ Ah, const unsigned short* __restrict__ Al,
                                      const unsigned short* __restrict__ Bh, const unsigned short* __restrict__ Bl,
                                      int s, int g, int m, int q) {
    f32x4 acc = fzero();
#pragma unroll
    for (int k0 = 0; k0 < 64; k0 += 32) {
        bf16x8 ah = *(const bf16x8*)&Ah[(16 * s + m) * 72 + k0 + 8 * q];
        bf16x8 al = *(const bf16x8*)&Al[(16 * s + m) * 72 + k0 + 8 * q];
        bf16x8 bh = *(const bf16x8*)&Bh[(16 * g + m) * 72 + k0 + 8 * q];
        bf16x8 bl = *(const bf16x8*)&Bl[(16 * g + m) * 72 + k0 + 8 * q];
        acc = mfma16(ah, bh, acc);
        acc = mfma16(ah, bl, acc);
        acc = mfma16(al, bh, acc);
    }
#pragma unroll
    for (int r = 0; r < 4; ++r) {
        int row = 16 * s + 4 * q + r, col = 16 * g + m;
        float v = acc[r];
        unsigned u = __float_as_uint(v);
        Dh[row * 72 + col] = (unsigned short)(u >> 16);
        float res = v - __uint_as_float(u & 0xFFFF0000u);
        Dl[row * 72 + col] = (unsigned short)(__float_as_uint(res) >> 16);
    }
}

__global__ __launch_bounds__(1024) void ns_kernel(float* __restrict__ ws) {
    __shared__ __align__(16) float Pm[64 * 68];
    __shared__ __align__(16) unsigned short Sh[64 * 72],  Sl[64 * 72];
    __shared__ __align__(16) unsigned short Ph[64 * 72],  Plo[64 * 72];
    __shared__ __align__(16) unsigned short T1h[64 * 72], T1l[64 * 72];
    __shared__ __align__(16) unsigned short T2h[64 * 72], T2l[64 * 72];
    __shared__ float mu[64];
    __shared__ float scal[2];

    const int tid = threadIdx.x;
    const int w16 = tid >> 6;
    const int s = w16 >> 2, g = w16 & 3;
    const int lane = tid & 63;
    const int m = lane & 15, q = lane >> 4;
    const float inv_m = 1.0f / M_TOT_F;

    if (tid < 64) mu[tid] = ws[8192 + tid] * inv_m;
    __syncthreads();

    // Sigma into Pm (scratch, stride 68)
    for (int e = tid; e < 4096; e += 1024) {
        int i = e >> 6, j = e & 63;
        float gv = (ws[e] + ws[4096 + e] + ws[4096 + (j << 6) + i]) * inv_m;
        Pm[i * 68 + j] = gv - mu[i] * mu[j] + ((i == j) ? EPS_F : 0.f);
    }
    __syncthreads();

    if (tid < 64) {
        float v = Pm[tid * 68 + tid];
#pragma unroll
        for (int off = 32; off >= 1; off >>= 1) v += __shfl_xor(v, off);
        if (tid == 0) { scal[0] = 1.0f / v; scal[1] = sqrtf(1.0f / v); }
    }
    __syncthreads();
    const float rTr = scal[0];

    // S planes = Sigma_N (hi/lo); Pm -> I; P planes = I
    for (int e = tid; e < 4096; e += 1024) {
        int i = e >> 6, j = e & 63;
        float v = Pm[i * 68 + j] * rTr;
        unsigned u = __float_as_uint(v);
        Sh[i * 72 + j] = (unsigned short)(u >> 16);
        float res = v - __uint_as_float(u & 0xFFFF0000u);
        Sl[i * 72 + j] = (unsigned short)(__float_as_uint(res) >> 16);
        Pm[i * 68 + j] = (i == j) ? 1.f : 0.f;
        Ph[i * 72 + j] = (i == j) ? (unsigned short)0x3F80 : (unsigned short)0;
        Plo[i * 72 + j] = 0;
    }
    __syncthreads();

    for (int it = 0; it < 5; ++it) {
        ns_mm(T1h, T1l, Ph, Plo, Ph, Plo, s, g, m, q);   // T1 = P^2
        __syncthreads();
        ns_mm(T2h, T2l, T1h, T1l, Ph, Plo, s, g, m, q);  // T2 = P^3
        __syncthreads();
        // C = T2 * Sigma_N; P = 1.5P - 0.5C (fp32 master + refresh planes)
        f32x4 acc = fzero();
#pragma unroll
        for (int k0 = 0; k0 < 64; k0 += 32) {
            bf16x8 ah = *(const bf16x8*)&T2h[(16 * s + m) * 72 + k0 + 8 * q];
            bf16x8 al = *(const bf16x8*)&T2l[(16 * s + m) * 72 + k0 + 8 * q];
            bf16x8 bh = *(const bf16x8*)&Sh[(16 * g + m) * 72 + k0 + 8 * q];
            bf16x8 bl = *(const bf16x8*)&Sl[(16 * g + m) * 72 + k0 + 8 * q];
            acc = mfma16(ah, bh, acc);
            acc = mfma16(ah, bl, acc);
            acc = mfma16(al, bh, acc);
        }
#pragma unroll
        for (int r = 0; r < 4; ++r) {
            int row = 16 * s + 4 * q + r, col = 16 * g + m;
            float pv = 1.5f * Pm[row * 68 + col] - 0.5f * acc[r];
            Pm[row * 68 + col] = pv;
            unsigned u = __float_as_uint(pv);
            Ph[row * 72 + col] = (unsigned short)(u >> 16);
            float res = pv - __uint_as_float(u & 0xFFFF0000u);
            Plo[row * 72 + col] = (unsigned short)(__float_as_uint(res) >> 16);
        }
        __syncthreads();
    }

    // epilogue: wm = P*sqrt(rTr) -> bf16 hi/lo planes (global ws); bias fp32
    const float sc = scal[1];
    unsigned short* hp = (unsigned short*)ws;
    unsigned short* lp = hp + 4096;
    for (int e = tid; e < 4096; e += 1024) {
        int i = e >> 6, j = e & 63;
        float v = Pm[i * 68 + j] * sc;
        unsigned u = __float_as_uint(v);
        hp[e] = (unsigned short)(u >> 16);
        float r = v - __uint_as_float(u & 0xFFFF0000u);
        lp[e] = (unsigned short)(__float_as_uint(r) >> 16);
    }
    if (tid < 64) {
        float a = 0.f;
#pragma unroll 8
        for (int k = 0; k < 64; ++k) a += Pm[tid * 68 + k] * mu[k];
        ws[8256 + tid] = -a * sc;
    }
}

// ---------------- K3: Y = wm @ x + bias -- operand-swapped: D[row=l][col=c] ------------
// A = x (LDS transposed planes, wave-strip reads, nb-independent)
// B = wm (16 hi/lo frags hoisted into registers, symmetric row reads)
// Epilogue: lane owns 4 consecutive l at fixed channel -> global_store_dwordx4.
#define ATPB 4
__global__ __launch_bounds__(256) void apply_kernel(const float* __restrict__ X,
                                                    float* __restrict__ Y,
                                                    const float* __restrict__ ws) {
    __shared__ __align__(16) unsigned short hplane[4096];
    __shared__ __align__(16) unsigned short lplane[4096];
    const int tid  = threadIdx.x;
    const int w    = tid >> 6;
    const int lane = tid & 63;
    const int m    = lane & 15;
    const int q    = lane >> 4;
    const int cp   = tid & 31;      // channel pair rows 2cp, 2cp+1 (staging)
    const int lg   = tid >> 5;      // 0..7 (staging)

    const unsigned short* hp = (const unsigned short*)ws;
    const unsigned short* lp = hp + 4096;
    bf16x8 Wh[4][2], Wl[4][2];
#pragma unroll
    for (int nb = 0; nb < 4; ++nb)
#pragma unroll
        for (int kk = 0; kk < 2; ++kk) {
            Wh[nb][kk] = *(const bf16x8*)&hp[(16 * nb + m) * 64 + 32 * kk + 8 * q];
            Wl[nb][kk] = *(const bf16x8*)&lp[(16 * nb + m) * 64 + 32 * kk + 8 * q];
        }
    float biasv[4];
#pragma unroll
    for (int nb = 0; nb < 4; ++nb) biasv[nb] = ws[8256 + 16 * nb + m];

    unsigned* hw = (unsigned*)hplane;
    unsigned* lw = (unsigned*)lplane;

    float4 va[2], vb[2];
    {
        int tile = blockIdx.x * ATPB;
        const float* xb = X + (size_t)(tile >> 7) * (NCH * L_DIM) + ((tile & 127) << 6)
                          + (size_t)(2 * cp) * L_DIM + 4 * lg;
#pragma unroll
        for (int ss = 0; ss < 2; ++ss) {
            va[ss] = *(const float4*)(xb + 32 * ss);
            vb[ss] = *(const float4*)(xb + 32 * ss + L_DIM);
        }
    }

    for (int t = 0; t < ATPB; ++t) {
        int tile = blockIdx.x * ATPB + t;
        int bidx = tile >> 7;
        int l0   = (tile & 127) << 6;

        __syncthreads();
#pragma unroll
        for (int ss = 0; ss < 2; ++ss) {
            float fa[4], fb[4];
            *(float4*)fa = va[ss];
            *(float4*)fb = vb[ss];
#pragma unroll
            for (int i = 0; i < 4; ++i) {
                int l = 4 * lg + 32 * ss + i;
                unsigned h, lo2;
                cvt2(fa[i], fb[i], h, lo2);
                int widx = l * 32 + (((cp >> 2) ^ (l & 7)) << 2) + (cp & 3);
                hw[widx] = h;
                lw[widx] = lo2;
            }
        }
        __syncthreads();

        if (t + 1 < ATPB) {
            int tn = tile + 1;
            const float* xb = X + (size_t)(tn >> 7) * (NCH * L_DIM) + ((tn & 127) << 6)
                              + (size_t)(2 * cp) * L_DIM + 4 * lg;
#pragma unroll
            for (int ss = 0; ss < 2; ++ss) {
                va[ss] = *(const float4*)(xb + 32 * ss);
                vb[ss] = *(const float4*)(xb + 32 * ss + L_DIM);
            }
        }

        f32x4 acc[4];
#pragma unroll
        for (int nb = 0; nb < 4; ++nb) {
            acc[nb][0] = biasv[nb]; acc[nb][1] = biasv[nb];
            acc[nb][2] = biasv[nb]; acc[nb][3] = biasv[nb];
        }
#pragma unroll
        for (int kk = 0; kk < 2; ++kk) {
            const int l = 16 * w + m;
            const int saddr = l * 64 + ((((4 * kk + q) ^ (l & 7))) << 3);
            bf16x8 xh = *(const bf16x8*)&hplane[saddr];
            bf16x8 xl = *(const bf16x8*)&lplane[saddr];
#pragma unroll
            for (int nb = 0; nb < 4; ++nb) {
                acc[nb] = mfma16(xh, Wh[nb][kk], acc[nb]);
                acc[nb] = mfma16(xh, Wl[nb][kk], acc[nb]);
                acc[nb] = mfma16(xl, Wh[nb][kk], acc[nb]);
            }
        }

#pragma unroll
        for (int nb = 0; nb < 4; ++nb) {
            float4 o;
            o.x = acc[nb][0]; o.y = acc[nb][1]; o.z = acc[nb][2]; o.w = acc[nb][3];
            *(float4*)&Y[((size_t)bidx * NCH + 16 * nb + m) * L_DIM + l0 + 16 * w + 4 * q] = o;
        }
    }
}

extern "C" void kernel_launch(void* const* d_in, const int* in_sizes, int n_in,
                              void* d_out, int out_size, void* d_ws, size_t ws_size,
                              hipStream_t stream) {
    const float* X = (const float*)d_in[0];
    float* Y  = (float*)d_out;
    float* ws = (float*)d_ws;
    float* scratch = (float*)d_out;   // gram partials live in d_out before apply overwrites it

    hipLaunchKernelGGL(gram_kernel,   dim3(512),  dim3(256), 0, stream, X, scratch);
    hipLaunchKernelGGL(reduce_kernel, dim3(129),  dim3(256), 0, stream, scratch, ws);
    hipLaunchKernelGGL(ns_kernel,     dim3(1),    dim3(1024), 0, stream, ws);
    hipLaunchKernelGGL(apply_kernel,  dim3(1024), dim3(256), 0, stream, X, Y, ws);
}